// Round 21
// baseline (295.748 us; speedup 1.0000x reference)
//
#include <hip/hip_runtime.h>
#include <hip/hip_bf16.h>
#include <cstdint>
#include <cstddef>

constexpr int Bc = 4, Lc = 4096, Dc = 768, Nc = 16;
constexpr int M_TOT = Bc * Lc;     // 16384
constexpr int NCH = 256;           // chunks per sequence (was 128)
constexpr int TCH = Lc / NCH;      // 16
constexpr int Kd = 768;            // K of all GEMMs
constexpr int TWO_D = 1536;
constexpr int NDTBC = 896;         // fused [dt | B,C | pad] width (7*128)

typedef __attribute__((ext_vector_type(8))) short short8v;   // 8 bf16 (4 VGPRs)
typedef __attribute__((ext_vector_type(4))) float f32x4;     // MFMA acc

__device__ __forceinline__ float fexp2(float x) {
#if __has_builtin(__builtin_amdgcn_exp2f)
    return __builtin_amdgcn_exp2f(x);
#else
    return exp2f(x);
#endif
}
__device__ __forceinline__ float softplusf(float x) {
    return (x > 20.0f) ? x : __logf(1.0f + __expf(x));
}
__device__ __forceinline__ float siluf(float x) {
    return x / (1.0f + __expf(-x));
}
__device__ __forceinline__ float bf16lo(uint32_t v) {
    return __uint_as_float(v << 16);
}
__device__ __forceinline__ float bf16hi(uint32_t v) {
    return __uint_as_float(v & 0xffff0000u);
}

// XCD-aware tile swizzle (T1; grids 1536/896/768, all %8==0 -> bijective).
__device__ __forceinline__ void swizzled_tile(int& row0, int& col0)
{
    const int nwg = gridDim.x * gridDim.y;
    const int bid = blockIdx.y * gridDim.x + blockIdx.x;
    const int swz = (bid & 7) * (nwg >> 3) + (bid >> 3);
    row0 = (swz / gridDim.x) * 128;
    col0 = (swz % gridDim.x) * 128;
}

// ---------- bf16 MFMA GEMM, fp32 out (HW-verified core + T1; NON-TEMPLATE) ----------
__global__ __launch_bounds__(256)
void gemm_bf16_f32(const __hip_bfloat16* __restrict__ Ab,
                   const __hip_bfloat16* __restrict__ Wt,
                   int N, float* __restrict__ out0)
{
    __shared__ __hip_bfloat16 Asm[128 * 32];
    __shared__ __hip_bfloat16 Bsm[128 * 32];
    const int tid = threadIdx.x;
    const int w = tid >> 6, lane = tid & 63;
    const int lr = lane & 15, lc = lane >> 4;
    int row0, col0;
    swizzled_tile(row0, col0);
    const int wrow = (w >> 1) * 64, wcol = (w & 1) * 64;

    const int srow = lane >> 2;
    const int scol = (lane & 3) * 8;

    f32x4 acc[4][4] = {};

    const int KT = Kd / 32;
    for (int kt = 0; kt < KT; ++kt) {
        if (kt) __syncthreads();
        #pragma unroll
        for (int i = 0; i < 2; ++i) {
            const int seg = w * 2 + i;
            const __hip_bfloat16* asrc =
                Ab + (size_t)(row0 + seg * 16 + srow) * Kd + kt * 32 + scol;
            const __hip_bfloat16* bsrc =
                Wt + (size_t)(col0 + seg * 16 + srow) * Kd + kt * 32 + scol;
            __builtin_amdgcn_global_load_lds(
                (const __attribute__((address_space(1))) void*)asrc,
                (__attribute__((address_space(3))) void*)(Asm + seg * 512), 16, 0, 0);
            __builtin_amdgcn_global_load_lds(
                (const __attribute__((address_space(1))) void*)bsrc,
                (__attribute__((address_space(3))) void*)(Bsm + seg * 512), 16, 0, 0);
        }
        asm volatile("s_waitcnt vmcnt(0)" ::: "memory");
        __syncthreads();

        short8v a[4], b[4];
        #pragma unroll
        for (int m = 0; m < 4; ++m)
            a[m] = *(const short8v*)((char*)Asm + (wrow + m * 16 + lr) * 64 + lc * 16);
        #pragma unroll
        for (int nf = 0; nf < 4; ++nf)
            b[nf] = *(const short8v*)((char*)Bsm + (wcol + nf * 16 + lr) * 64 + lc * 16);
        #pragma unroll
        for (int m = 0; m < 4; ++m)
            #pragma unroll
            for (int nf = 0; nf < 4; ++nf)
                acc[m][nf] = __builtin_amdgcn_mfma_f32_16x16x32_bf16(
                    a[m], b[nf], acc[m][nf], 0, 0, 0);
    }

    #pragma unroll
    for (int m = 0; m < 4; ++m)
        #pragma unroll
        for (int nf = 0; nf < 4; ++nf)
            #pragma unroll
            for (int j = 0; j < 4; ++j) {
                const int rg = row0 + wrow + m * 16 + lc * 4 + j;
                const int cg = col0 + wcol + nf * 16 + lr;
                out0[(size_t)rg * N + cg] = acc[m][nf][j];
            }
}

// ---------- bf16 MFMA GEMM, bf16 out (standalone, + T1) ----------
__global__ __launch_bounds__(256)
void gemm_bf16_b16(const __hip_bfloat16* __restrict__ Ab,
                   const __hip_bfloat16* __restrict__ Wt,
                   int N, __hip_bfloat16* __restrict__ outb)
{
    __shared__ __hip_bfloat16 Asm[128 * 32];
    __shared__ __hip_bfloat16 Bsm[128 * 32];
    const int tid = threadIdx.x;
    const int w = tid >> 6, lane = tid & 63;
    const int lr = lane & 15, lc = lane >> 4;
    int row0, col0;
    swizzled_tile(row0, col0);
    const int wrow = (w >> 1) * 64, wcol = (w & 1) * 64;

    const int srow = lane >> 2;
    const int scol = (lane & 3) * 8;

    f32x4 acc[4][4] = {};

    const int KT = Kd / 32;
    for (int kt = 0; kt < KT; ++kt) {
        if (kt) __syncthreads();
        #pragma unroll
        for (int i = 0; i < 2; ++i) {
            const int seg = w * 2 + i;
            const __hip_bfloat16* asrc =
                Ab + (size_t)(row0 + seg * 16 + srow) * Kd + kt * 32 + scol;
            const __hip_bfloat16* bsrc =
                Wt + (size_t)(col0 + seg * 16 + srow) * Kd + kt * 32 + scol;
            __builtin_amdgcn_global_load_lds(
                (const __attribute__((address_space(1))) void*)asrc,
                (__attribute__((address_space(3))) void*)(Asm + seg * 512), 16, 0, 0);
            __builtin_amdgcn_global_load_lds(
                (const __attribute__((address_space(1))) void*)bsrc,
                (__attribute__((address_space(3))) void*)(Bsm + seg * 512), 16, 0, 0);
        }
        asm volatile("s_waitcnt vmcnt(0)" ::: "memory");
        __syncthreads();

        short8v a[4], b[4];
        #pragma unroll
        for (int m = 0; m < 4; ++m)
            a[m] = *(const short8v*)((char*)Asm + (wrow + m * 16 + lr) * 64 + lc * 16);
        #pragma unroll
        for (int nf = 0; nf < 4; ++nf)
            b[nf] = *(const short8v*)((char*)Bsm + (wcol + nf * 16 + lr) * 64 + lc * 16);
        #pragma unroll
        for (int m = 0; m < 4; ++m)
            #pragma unroll
            for (int nf = 0; nf < 4; ++nf)
                acc[m][nf] = __builtin_amdgcn_mfma_f32_16x16x32_bf16(
                    a[m], b[nf], acc[m][nf], 0, 0, 0);
    }

    #pragma unroll
    for (int m = 0; m < 4; ++m)
        #pragma unroll
        for (int nf = 0; nf < 4; ++nf)
            #pragma unroll
            for (int j = 0; j < 4; ++j) {
                const int rg = row0 + wrow + m * 16 + lc * 4 + j;
                const int cg = col0 + wcol + nf * 16 + lr;
                outb[(size_t)rg * N + cg] = __float2bfloat16(acc[m][nf][j]);
            }
}

// ---------------- prep kernels ----------------
__global__ __launch_bounds__(256)
void to_bf16_kernel(const float* __restrict__ src, __hip_bfloat16* __restrict__ dst, int n4)
{
    const int i = blockIdx.x * 256 + threadIdx.x;
    if (i >= n4) return;
    const float4 v = ((const float4*)src)[i];
    dst[i * 4 + 0] = __float2bfloat16(v.x);
    dst[i * 4 + 1] = __float2bfloat16(v.y);
    dst[i * 4 + 2] = __float2bfloat16(v.z);
    dst[i * 4 + 3] = __float2bfloat16(v.w);
}

__global__ __launch_bounds__(256)
void wtrans_tile(const float* __restrict__ src, __hip_bfloat16* __restrict__ dst, int N)
{
    __shared__ float tile[32][33];
    const int n0 = blockIdx.x * 32, k0 = blockIdx.y * 32;
    const int tx = threadIdx.x & 31, ty = threadIdx.x >> 5;
    #pragma unroll
    for (int r = 0; r < 4; ++r) {
        const int k = ty + r * 8;
        tile[k][tx] = src[(size_t)(k0 + k) * N + n0 + tx];
    }
    __syncthreads();
    #pragma unroll
    for (int r = 0; r < 4; ++r) {
        const int n = ty + r * 8;
        dst[(size_t)(n0 + n) * Kd + k0 + tx] = __float2bfloat16(tile[tx][n]);
    }
}

__global__ __launch_bounds__(256)
void aprep_kernel(const float* __restrict__ A_log, float* __restrict__ Abuf)
{
    const int i = blockIdx.x * 256 + threadIdx.x;
    if (i < Dc * Nc) Abuf[i] = -expf(A_log[i]) * 1.4426950408889634f;
}

// ---------------- t-blocked conv + silu (R20, HW-verified) ----------------
__global__ __launch_bounds__(256)
void conv_silu_kernel(const __hip_bfloat16* __restrict__ xz16, const float* __restrict__ cw,
                      const float* __restrict__ cb, __hip_bfloat16* __restrict__ xsb)
{
    const int ND2 = Dc / 2;
    const int idx = blockIdx.x * 256 + threadIdx.x;
    if (idx >= (M_TOT / 8) * ND2) return;
    const int d0 = (idx % ND2) * 2;
    const int r8 = idx / ND2;
    const int tb = r8 & (Lc / 8 - 1);
    const int b = r8 / (Lc / 8);
    const int t0 = tb * 8;
    const size_t rbase = (size_t)(b * Lc + t0);

    const float w00 = cw[d0 * 4 + 0], w01 = cw[d0 * 4 + 1],
                w02 = cw[d0 * 4 + 2], w03 = cw[d0 * 4 + 3];
    const float w10 = cw[d0 * 4 + 4], w11 = cw[d0 * 4 + 5],
                w12 = cw[d0 * 4 + 6], w13 = cw[d0 * 4 + 7];
    const float bias0 = cb[d0], bias1 = cb[d0 + 1];

    float a3 = 0.f, a2 = 0.f, a1 = 0.f;
    float b3 = 0.f, b2 = 0.f, b1 = 0.f;
    if (t0 >= 3) {
        const uint32_t v3 = *(const uint32_t*)(xz16 + (rbase - 3) * TWO_D + d0);
        const uint32_t v2 = *(const uint32_t*)(xz16 + (rbase - 2) * TWO_D + d0);
        const uint32_t v1 = *(const uint32_t*)(xz16 + (rbase - 1) * TWO_D + d0);
        a3 = bf16lo(v3); b3 = bf16hi(v3);
        a2 = bf16lo(v2); b2 = bf16hi(v2);
        a1 = bf16lo(v1); b1 = bf16hi(v1);
    }
    #pragma unroll
    for (int tt = 0; tt < 8; ++tt) {
        const uint32_t v0 = *(const uint32_t*)(xz16 + (rbase + tt) * TWO_D + d0);
        const float x0a = bf16lo(v0), x0b = bf16hi(v0);
        const float ra = siluf(fmaf(w03, x0a, fmaf(w02, a1, fmaf(w01, a2, fmaf(w00, a3, bias0)))));
        const float rb = siluf(fmaf(w13, x0b, fmaf(w12, b1, fmaf(w11, b2, fmaf(w10, b3, bias1)))));
        __hip_bfloat16 o2[2] = { __float2bfloat16(ra), __float2bfloat16(rb) };
        *(uint32_t*)(xsb + (rbase + tt) * Dc + d0) = *(const uint32_t*)o2;
        a3 = a2; a2 = a1; a1 = x0a;
        b3 = b2; b2 = b1; b1 = x0b;
    }
}

// ---------------- chunked scan (NCH=256, TCH=16) ----------------
__global__ __launch_bounds__(256)
void scanA(float* __restrict__ dtbc, const __hip_bfloat16* __restrict__ xsb,
           const float* __restrict__ Abuf, const float* __restrict__ bdt,
           float* __restrict__ S, float* __restrict__ dcend)
{
    const int blk = blockIdx.x;
    const int dblk = blk % 3, ch = (blk / 3) % NCH, b = blk / (3 * NCH);
    const int d = dblk * 256 + threadIdx.x;
    const int t0 = ch * TCH;
    const size_t brow = (size_t)(b * Lc + t0);

    __shared__ float bcs[TCH * 32];   // 2 KB: TCH=16 rows x 32
    {
        const int row = threadIdx.x >> 4, c2 = (threadIdx.x & 15) * 2;   // float2/thread
        *(float2*)&bcs[row * 32 + c2] =
            *(const float2*)(dtbc + (brow + row) * NDTBC + Dc + c2);
    }
    __syncthreads();

    float A[16];
    #pragma unroll
    for (int q = 0; q < 4; ++q)
        *(float4*)&A[q * 4] = *(const float4*)(Abuf + d * 16 + q * 4);
    const float bd = bdt[d];

    float s[16];
    #pragma unroll
    for (int n = 0; n < 16; ++n) s[n] = 0.f;

    float dc = 0.f;
    #pragma unroll 4
    for (int t = 0; t < TCH; ++t) {
        const size_t doff = (brow + t) * NDTBC + d;
        const float dt = softplusf(dtbc[doff] + bd);
        dtbc[doff] = dt;                               // cache for scanC
        const float x = __bfloat162float(xsb[(brow + t) * Dc + d]);
        dc += dt;
        float Bt[16];
        #pragma unroll
        for (int q = 0; q < 4; ++q)
            *(float4*)&Bt[q * 4] = *(const float4*)&bcs[t * 32 + q * 4];
        #pragma unroll
        for (int n = 0; n < 16; ++n) {
            const float dA = fexp2(dt * A[n]);
            s[n] = fmaf(s[n], dA, Bt[n] * x);
        }
    }
    const size_t g = (size_t)(b * NCH + ch) * Dc + d;
    #pragma unroll
    for (int n = 0; n < 16; ++n) S[g * 16 + n] = s[n];
    dcend[g] = dc;
}

__global__ __launch_bounds__(256)
void scanB(float* __restrict__ S_io, const float* __restrict__ dcend,
           const float* __restrict__ Abuf)
{
    const int tid = blockIdx.x * 256 + threadIdx.x;
    const int n = tid & 15;
    const int d = (tid >> 4) % Dc;
    const int b = tid / (16 * Dc);
    const float An = Abuf[d * 16 + n];
    float s = 0.f;
    for (int ch = 0; ch < NCH; ++ch) {
        const size_t g = (size_t)(b * NCH + ch) * Dc + d;
        const float sv = S_io[g * 16 + n];
        const float p  = fexp2(dcend[g] * An);
        S_io[g * 16 + n] = s;
        s = fmaf(s, p, sv);
    }
}

__global__ __launch_bounds__(256)
void scanC(const float* __restrict__ dtbc, const __hip_bfloat16* __restrict__ xsb,
           const __hip_bfloat16* __restrict__ xz16,
           const float* __restrict__ Abuf,
           const float* __restrict__ Ibuf, const float* __restrict__ Dvec,
           __hip_bfloat16* __restrict__ ybf)
{
    const int blk = blockIdx.x;
    const int dblk = blk % 3, ch = (blk / 3) % NCH, b = blk / (3 * NCH);
    const int d = dblk * 256 + threadIdx.x;
    const int t0 = ch * TCH;
    const size_t brow = (size_t)(b * Lc + t0);

    __shared__ float bcs[TCH * 32];
    {
        const int row = threadIdx.x >> 4, c2 = (threadIdx.x & 15) * 2;
        *(float2*)&bcs[row * 32 + c2] =
            *(const float2*)(dtbc + (brow + row) * NDTBC + Dc + c2);
    }
    __syncthreads();

    float A[16], s[16];
    #pragma unroll
    for (int q = 0; q < 4; ++q)
        *(float4*)&A[q * 4] = *(const float4*)(Abuf + d * 16 + q * 4);
    const size_t g = (size_t)(b * NCH + ch) * Dc + d;
    #pragma unroll
    for (int q = 0; q < 4; ++q)
        *(float4*)&s[q * 4] = *(const float4*)(Ibuf + g * 16 + q * 4);
    const float Dd = Dvec[d];

    #pragma unroll 4
    for (int t = 0; t < TCH; ++t) {
        const float dt = dtbc[(brow + t) * NDTBC + d];   // pre-softplus'd
        const float x  = __bfloat162float(xsb[(brow + t) * Dc + d]);
        const float z  = __bfloat162float(xz16[(brow + t) * TWO_D + Dc + d]);
        float Bt[16], Ct[16];
        #pragma unroll
        for (int q = 0; q < 4; ++q) {
            *(float4*)&Bt[q * 4] = *(const float4*)&bcs[t * 32 + q * 4];
            *(float4*)&Ct[q * 4] = *(const float4*)&bcs[t * 32 + 16 + q * 4];
        }
        float yl = fmaf(Dd, x, 0.f);
        #pragma unroll
        for (int n = 0; n < 16; ++n) {
            const float dA = fexp2(dt * A[n]);
            s[n] = fmaf(s[n], dA, Bt[n] * x);
            yl = fmaf(s[n], Ct[n], yl);
        }
        ybf[(brow + t) * Dc + d] = __float2bfloat16(yl * siluf(z));
    }
}

extern "C" void kernel_launch(void* const* d_in, const int* in_sizes, int n_in,
                              void* d_out, int out_size, void* d_ws, size_t ws_size,
                              hipStream_t stream)
{
    const float* x      = (const float*)d_in[0];
    const float* state  = (const float*)d_in[1];
    const float* W_in   = (const float*)d_in[2];
    const float* conv_w = (const float*)d_in[3];
    const float* conv_b = (const float*)d_in[4];
    const float* W_x    = (const float*)d_in[5];
    const float* W_dt   = (const float*)d_in[6];
    const float* b_dt   = (const float*)d_in[7];
    const float* A_log  = (const float*)d_in[8];
    const float* Dvec   = (const float*)d_in[9];
    const float* W_out  = (const float*)d_in[10];
    float* out = (float*)d_out;

    // ---- workspace (~218 MB <= 253.75 verified) ----
    char* wsb = (char*)d_ws;
    __hip_bfloat16* xz16 = (__hip_bfloat16*)wsb;     wsb += (size_t)M_TOT * TWO_D * 2;
    float* dtbc  = (float*)wsb;                      wsb += (size_t)M_TOT * NDTBC * 4;
    float* Sb    = (float*)wsb;                      wsb += (size_t)Bc * NCH * Dc * Nc * 4;
    float* dcend = (float*)wsb;                      wsb += (size_t)Bc * NCH * Dc * 4;
    __hip_bfloat16* xb  = (__hip_bfloat16*)wsb;      wsb += (size_t)M_TOT * Dc * 2;
    __hip_bfloat16* xsb = (__hip_bfloat16*)wsb;      wsb += (size_t)M_TOT * Dc * 2;
    float* Abuf = (float*)wsb;                       wsb += (size_t)Dc * Nc * 4;
    __hip_bfloat16* WinT  = (__hip_bfloat16*)wsb;    wsb += (size_t)1536 * Kd * 2;
    __hip_bfloat16* WcatT = (__hip_bfloat16*)wsb;    wsb += (size_t)NDTBC * Kd * 2;
    __hip_bfloat16* WoutT = (__hip_bfloat16*)wsb;    wsb += (size_t)768 * Kd * 2;
    float* Ib = Sb;                               // scanB in-place (verified)
    __hip_bfloat16* ybf = xb;                     // xb dead after in_proj

    // ---- prep (no memset; no templates) ----
    to_bf16_kernel<<<(M_TOT * Dc / 4 + 255) / 256, 256, 0, stream>>>(x, xb, M_TOT * Dc / 4);
    wtrans_tile<<<dim3(1536 / 32, Kd / 32), 256, 0, stream>>>(W_in, WinT, 1536);
    wtrans_tile<<<dim3(768 / 32, Kd / 32), 256, 0, stream>>>(W_dt, WcatT, 768);
    wtrans_tile<<<dim3(32 / 32, Kd / 32), 256, 0, stream>>>(W_x, WcatT + (size_t)768 * Kd, 32);
    wtrans_tile<<<dim3(768 / 32, Kd / 32), 256, 0, stream>>>(W_out, WoutT, 768);
    aprep_kernel<<<(Dc * Nc + 255) / 256, 256, 0, stream>>>(A_log, Abuf);

    // 1) in_proj fused N=1536, bf16 out
    gemm_bf16_b16<<<dim3(TWO_D / 128, M_TOT / 128), 256, 0, stream>>>(
        xb, WinT, TWO_D, xz16);
    // 2) conv + silu -> bf16 xsb
    conv_silu_kernel<<<((M_TOT / 8) * (Dc / 2) + 255) / 256, 256, 0, stream>>>(
        xz16, conv_w, conv_b, xsb);
    // 3) fused dt|BC: dtbc = xsb @ [W_dt|W_x|pad], N=896
    gemm_bf16_f32<<<dim3(NDTBC / 128, M_TOT / 128), 256, 0, stream>>>(
        xsb, WcatT, NDTBC, dtbc);
    // 4) scan (NCH=256 -> 3072 blocks = 12/CU)
    scanA<<<Bc * NCH * 3, 256, 0, stream>>>(dtbc, xsb, Abuf, b_dt, Sb, dcend);
    scanB<<<(Bc * Dc * Nc) / 256, 256, 0, stream>>>(Sb, dcend, Abuf);
    scanC<<<Bc * NCH * 3, 256, 0, stream>>>(dtbc, xsb, xz16, Abuf, Ib, Dvec, ybf);
    // 5) out = y @ W_out (N=768)
    gemm_bf16_f32<<<dim3(Dc / 128, M_TOT / 128), 256, 0, stream>>>(ybf, WoutT, Dc, out);
    // 6) state pass-through
    hipMemcpyAsync(out + (size_t)M_TOT * Dc, state,
                   (size_t)(Bc * Dc * Nc) * sizeof(float),
                   hipMemcpyDeviceToDevice, stream);
}

// Round 22
// 260.500 us; speedup vs baseline: 1.1353x; 1.1353x over previous
//
#include <hip/hip_runtime.h>
#include <hip/hip_bf16.h>
#include <cstdint>
#include <cstddef>

constexpr int Bc = 4, Lc = 4096, Dc = 768, Nc = 16;
constexpr int M_TOT = Bc * Lc;     // 16384
constexpr int NCH = 128;           // chunks per sequence (reverted from 256)
constexpr int TCH = Lc / NCH;      // 32
constexpr int Kd = 768;            // K of all GEMMs
constexpr int TWO_D = 1536;
constexpr int NDTBC = 896;         // fused [dt | B,C | pad] width (7*128)

typedef __attribute__((ext_vector_type(8))) short short8v;   // 8 bf16 (4 VGPRs)
typedef __attribute__((ext_vector_type(4))) float f32x4;     // MFMA acc

__device__ __forceinline__ float fexp2(float x) {
#if __has_builtin(__builtin_amdgcn_exp2f)
    return __builtin_amdgcn_exp2f(x);
#else
    return exp2f(x);
#endif
}
__device__ __forceinline__ float softplusf(float x) {
    return (x > 20.0f) ? x : __logf(1.0f + __expf(x));
}
__device__ __forceinline__ float siluf(float x) {
    return x / (1.0f + __expf(-x));
}
__device__ __forceinline__ float bf16lo(uint32_t v) {
    return __uint_as_float(v << 16);
}
__device__ __forceinline__ float bf16hi(uint32_t v) {
    return __uint_as_float(v & 0xffff0000u);
}

// XCD-aware tile swizzle (T1; grids 1536/896/768, all %8==0 -> bijective).
__device__ __forceinline__ void swizzled_tile(int& row0, int& col0)
{
    const int nwg = gridDim.x * gridDim.y;
    const int bid = blockIdx.y * gridDim.x + blockIdx.x;
    const int swz = (bid & 7) * (nwg >> 3) + (bid >> 3);
    row0 = (swz / gridDim.x) * 128;
    col0 = (swz % gridDim.x) * 128;
}

// ---------- bf16 MFMA GEMM, BK=64 + T2 swizzle, fp32 out (NON-TEMPLATE) ----------
// LDS [128 rows][64 bf16] (128 B rows), 32 KB/operand-pair x2 = 32 KB total.
// Staging: global_load_lds writes LINEAR dest; source col pre-swizzled
// (rule #21): lane l covers row g*8 + (l>>3), src col 8*((l&7)^(l>>3)).
// Read: byte-in-row = (kk*64 + lc*16) ^ ((lr&7)<<4)  -> conflict-free.
__global__ __launch_bounds__(256)
void gemm_bf16_f32(const __hip_bfloat16* __restrict__ Ab,
                   const __hip_bfloat16* __restrict__ Wt,
                   int N, float* __restrict__ out0)
{
    __shared__ __hip_bfloat16 Asm[128 * 64];
    __shared__ __hip_bfloat16 Bsm[128 * 64];
    const int tid = threadIdx.x;
    const int w = tid >> 6, lane = tid & 63;
    const int lr = lane & 15, lc = lane >> 4;
    int row0, col0;
    swizzled_tile(row0, col0);
    const int wrow = (w >> 1) * 64, wcol = (w & 1) * 64;

    const int grow = lane >> 3;                       // row within 8-row group
    const int gcol = 8 * ((lane & 7) ^ (lane >> 3));  // pre-swizzled src col
    const int rsw = (lr & 7) << 4;                    // read-side XOR

    f32x4 acc[4][4] = {};

    const int KT = Kd / 64;   // 12
    for (int kt = 0; kt < KT; ++kt) {
        if (kt) __syncthreads();
        #pragma unroll
        for (int i = 0; i < 4; ++i) {
            const int g = w * 4 + i;                  // 8-row group 0..15
            const __hip_bfloat16* asrc =
                Ab + (size_t)(row0 + g * 8 + grow) * Kd + kt * 64 + gcol;
            const __hip_bfloat16* bsrc =
                Wt + (size_t)(col0 + g * 8 + grow) * Kd + kt * 64 + gcol;
            __builtin_amdgcn_global_load_lds(
                (const __attribute__((address_space(1))) void*)asrc,
                (__attribute__((address_space(3))) void*)(Asm + g * 512), 16, 0, 0);
            __builtin_amdgcn_global_load_lds(
                (const __attribute__((address_space(1))) void*)bsrc,
                (__attribute__((address_space(3))) void*)(Bsm + g * 512), 16, 0, 0);
        }
        asm volatile("s_waitcnt vmcnt(0)" ::: "memory");
        __syncthreads();

        #pragma unroll
        for (int kk = 0; kk < 2; ++kk) {
            const int rq = (kk * 64 + lc * 16) ^ rsw;
            short8v a[4], b[4];
            #pragma unroll
            for (int m = 0; m < 4; ++m)
                a[m] = *(const short8v*)((char*)Asm + (wrow + m * 16 + lr) * 128 + rq);
            #pragma unroll
            for (int nf = 0; nf < 4; ++nf)
                b[nf] = *(const short8v*)((char*)Bsm + (wcol + nf * 16 + lr) * 128 + rq);
            #pragma unroll
            for (int m = 0; m < 4; ++m)
                #pragma unroll
                for (int nf = 0; nf < 4; ++nf)
                    acc[m][nf] = __builtin_amdgcn_mfma_f32_16x16x32_bf16(
                        a[m], b[nf], acc[m][nf], 0, 0, 0);
        }
    }

    #pragma unroll
    for (int m = 0; m < 4; ++m)
        #pragma unroll
        for (int nf = 0; nf < 4; ++nf)
            #pragma unroll
            for (int j = 0; j < 4; ++j) {
                const int rg = row0 + wrow + m * 16 + lc * 4 + j;
                const int cg = col0 + wcol + nf * 16 + lr;
                out0[(size_t)rg * N + cg] = acc[m][nf][j];
            }
}

// ---------- same BK=64 body, bf16 out (SEPARATE non-template kernel) ----------
__global__ __launch_bounds__(256)
void gemm_bf16_b16(const __hip_bfloat16* __restrict__ Ab,
                   const __hip_bfloat16* __restrict__ Wt,
                   int N, __hip_bfloat16* __restrict__ outb)
{
    __shared__ __hip_bfloat16 Asm[128 * 64];
    __shared__ __hip_bfloat16 Bsm[128 * 64];
    const int tid = threadIdx.x;
    const int w = tid >> 6, lane = tid & 63;
    const int lr = lane & 15, lc = lane >> 4;
    int row0, col0;
    swizzled_tile(row0, col0);
    const int wrow = (w >> 1) * 64, wcol = (w & 1) * 64;

    const int grow = lane >> 3;
    const int gcol = 8 * ((lane & 7) ^ (lane >> 3));
    const int rsw = (lr & 7) << 4;

    f32x4 acc[4][4] = {};

    const int KT = Kd / 64;
    for (int kt = 0; kt < KT; ++kt) {
        if (kt) __syncthreads();
        #pragma unroll
        for (int i = 0; i < 4; ++i) {
            const int g = w * 4 + i;
            const __hip_bfloat16* asrc =
                Ab + (size_t)(row0 + g * 8 + grow) * Kd + kt * 64 + gcol;
            const __hip_bfloat16* bsrc =
                Wt + (size_t)(col0 + g * 8 + grow) * Kd + kt * 64 + gcol;
            __builtin_amdgcn_global_load_lds(
                (const __attribute__((address_space(1))) void*)asrc,
                (__attribute__((address_space(3))) void*)(Asm + g * 512), 16, 0, 0);
            __builtin_amdgcn_global_load_lds(
                (const __attribute__((address_space(1))) void*)bsrc,
                (__attribute__((address_space(3))) void*)(Bsm + g * 512), 16, 0, 0);
        }
        asm volatile("s_waitcnt vmcnt(0)" ::: "memory");
        __syncthreads();

        #pragma unroll
        for (int kk = 0; kk < 2; ++kk) {
            const int rq = (kk * 64 + lc * 16) ^ rsw;
            short8v a[4], b[4];
            #pragma unroll
            for (int m = 0; m < 4; ++m)
                a[m] = *(const short8v*)((char*)Asm + (wrow + m * 16 + lr) * 128 + rq);
            #pragma unroll
            for (int nf = 0; nf < 4; ++nf)
                b[nf] = *(const short8v*)((char*)Bsm + (wcol + nf * 16 + lr) * 128 + rq);
            #pragma unroll
            for (int m = 0; m < 4; ++m)
                #pragma unroll
                for (int nf = 0; nf < 4; ++nf)
                    acc[m][nf] = __builtin_amdgcn_mfma_f32_16x16x32_bf16(
                        a[m], b[nf], acc[m][nf], 0, 0, 0);
        }
    }

    #pragma unroll
    for (int m = 0; m < 4; ++m)
        #pragma unroll
        for (int nf = 0; nf < 4; ++nf)
            #pragma unroll
            for (int j = 0; j < 4; ++j) {
                const int rg = row0 + wrow + m * 16 + lc * 4 + j;
                const int cg = col0 + wcol + nf * 16 + lr;
                outb[(size_t)rg * N + cg] = __float2bfloat16(acc[m][nf][j]);
            }
}

// ---------------- prep kernels (HW-verified) ----------------
__global__ __launch_bounds__(256)
void to_bf16_kernel(const float* __restrict__ src, __hip_bfloat16* __restrict__ dst, int n4)
{
    const int i = blockIdx.x * 256 + threadIdx.x;
    if (i >= n4) return;
    const float4 v = ((const float4*)src)[i];
    dst[i * 4 + 0] = __float2bfloat16(v.x);
    dst[i * 4 + 1] = __float2bfloat16(v.y);
    dst[i * 4 + 2] = __float2bfloat16(v.z);
    dst[i * 4 + 3] = __float2bfloat16(v.w);
}

__global__ __launch_bounds__(256)
void wtrans_tile(const float* __restrict__ src, __hip_bfloat16* __restrict__ dst, int N)
{
    __shared__ float tile[32][33];
    const int n0 = blockIdx.x * 32, k0 = blockIdx.y * 32;
    const int tx = threadIdx.x & 31, ty = threadIdx.x >> 5;
    #pragma unroll
    for (int r = 0; r < 4; ++r) {
        const int k = ty + r * 8;
        tile[k][tx] = src[(size_t)(k0 + k) * N + n0 + tx];
    }
    __syncthreads();
    #pragma unroll
    for (int r = 0; r < 4; ++r) {
        const int n = ty + r * 8;
        dst[(size_t)(n0 + n) * Kd + k0 + tx] = __float2bfloat16(tile[tx][n]);
    }
}

__global__ __launch_bounds__(256)
void aprep_kernel(const float* __restrict__ A_log, float* __restrict__ Abuf)
{
    const int i = blockIdx.x * 256 + threadIdx.x;
    if (i < Dc * Nc) Abuf[i] = -expf(A_log[i]) * 1.4426950408889634f;
}

// ---------------- t-blocked conv + silu (R20, HW-verified) ----------------
__global__ __launch_bounds__(256)
void conv_silu_kernel(const __hip_bfloat16* __restrict__ xz16, const float* __restrict__ cw,
                      const float* __restrict__ cb, __hip_bfloat16* __restrict__ xsb)
{
    const int ND2 = Dc / 2;
    const int idx = blockIdx.x * 256 + threadIdx.x;
    if (idx >= (M_TOT / 8) * ND2) return;
    const int d0 = (idx % ND2) * 2;
    const int r8 = idx / ND2;
    const int tb = r8 & (Lc / 8 - 1);
    const int b = r8 / (Lc / 8);
    const int t0 = tb * 8;
    const size_t rbase = (size_t)(b * Lc + t0);

    const float w00 = cw[d0 * 4 + 0], w01 = cw[d0 * 4 + 1],
                w02 = cw[d0 * 4 + 2], w03 = cw[d0 * 4 + 3];
    const float w10 = cw[d0 * 4 + 4], w11 = cw[d0 * 4 + 5],
                w12 = cw[d0 * 4 + 6], w13 = cw[d0 * 4 + 7];
    const float bias0 = cb[d0], bias1 = cb[d0 + 1];

    float a3 = 0.f, a2 = 0.f, a1 = 0.f;
    float b3 = 0.f, b2 = 0.f, b1 = 0.f;
    if (t0 >= 3) {
        const uint32_t v3 = *(const uint32_t*)(xz16 + (rbase - 3) * TWO_D + d0);
        const uint32_t v2 = *(const uint32_t*)(xz16 + (rbase - 2) * TWO_D + d0);
        const uint32_t v1 = *(const uint32_t*)(xz16 + (rbase - 1) * TWO_D + d0);
        a3 = bf16lo(v3); b3 = bf16hi(v3);
        a2 = bf16lo(v2); b2 = bf16hi(v2);
        a1 = bf16lo(v1); b1 = bf16hi(v1);
    }
    #pragma unroll
    for (int tt = 0; tt < 8; ++tt) {
        const uint32_t v0 = *(const uint32_t*)(xz16 + (rbase + tt) * TWO_D + d0);
        const float x0a = bf16lo(v0), x0b = bf16hi(v0);
        const float ra = siluf(fmaf(w03, x0a, fmaf(w02, a1, fmaf(w01, a2, fmaf(w00, a3, bias0)))));
        const float rb = siluf(fmaf(w13, x0b, fmaf(w12, b1, fmaf(w11, b2, fmaf(w10, b3, bias1)))));
        __hip_bfloat16 o2[2] = { __float2bfloat16(ra), __float2bfloat16(rb) };
        *(uint32_t*)(xsb + (rbase + tt) * Dc + d0) = *(const uint32_t*)o2;
        a3 = a2; a2 = a1; a1 = x0a;
        b3 = b2; b2 = b1; b1 = x0b;
    }
}

// ---------------- chunked scan (NCH=128 / TCH=32, R20-passing verbatim) ----------------
__global__ __launch_bounds__(256)
void scanA(float* __restrict__ dtbc, const __hip_bfloat16* __restrict__ xsb,
           const float* __restrict__ Abuf, const float* __restrict__ bdt,
           float* __restrict__ S, float* __restrict__ dcend)
{
    const int blk = blockIdx.x;
    const int dblk = blk % 3, ch = (blk / 3) % NCH, b = blk / (3 * NCH);
    const int d = dblk * 256 + threadIdx.x;
    const int t0 = ch * TCH;
    const size_t brow = (size_t)(b * Lc + t0);

    __shared__ float bcs[TCH * 32];
    {
        const int row = threadIdx.x >> 3, c4 = (threadIdx.x & 7) * 4;
        *(float4*)&bcs[row * 32 + c4] =
            *(const float4*)(dtbc + (brow + row) * NDTBC + Dc + c4);
    }
    __syncthreads();

    float A[16];
    #pragma unroll
    for (int q = 0; q < 4; ++q)
        *(float4*)&A[q * 4] = *(const float4*)(Abuf + d * 16 + q * 4);
    const float bd = bdt[d];

    float s[16];
    #pragma unroll
    for (int n = 0; n < 16; ++n) s[n] = 0.f;

    float dc = 0.f;
    #pragma unroll 4
    for (int t = 0; t < TCH; ++t) {
        const size_t doff = (brow + t) * NDTBC + d;
        const float dt = softplusf(dtbc[doff] + bd);
        dtbc[doff] = dt;                               // cache for scanC
        const float x = __bfloat162float(xsb[(brow + t) * Dc + d]);
        dc += dt;
        float Bt[16];
        #pragma unroll
        for (int q = 0; q < 4; ++q)
            *(float4*)&Bt[q * 4] = *(const float4*)&bcs[t * 32 + q * 4];
        #pragma unroll
        for (int n = 0; n < 16; ++n) {
            const float dA = fexp2(dt * A[n]);
            s[n] = fmaf(s[n], dA, Bt[n] * x);
        }
    }
    const size_t g = (size_t)(b * NCH + ch) * Dc + d;
    #pragma unroll
    for (int n = 0; n < 16; ++n) S[g * 16 + n] = s[n];
    dcend[g] = dc;
}

__global__ __launch_bounds__(256)
void scanB(float* __restrict__ S_io, const float* __restrict__ dcend,
           const float* __restrict__ Abuf)
{
    const int tid = blockIdx.x * 256 + threadIdx.x;
    const int n = tid & 15;
    const int d = (tid >> 4) % Dc;
    const int b = tid / (16 * Dc);
    const float An = Abuf[d * 16 + n];
    float s = 0.f;
    for (int ch = 0; ch < NCH; ++ch) {
        const size_t g = (size_t)(b * NCH + ch) * Dc + d;
        const float sv = S_io[g * 16 + n];
        const float p  = fexp2(dcend[g] * An);
        S_io[g * 16 + n] = s;
        s = fmaf(s, p, sv);
    }
}

__global__ __launch_bounds__(256)
void scanC(const float* __restrict__ dtbc, const __hip_bfloat16* __restrict__ xsb,
           const __hip_bfloat16* __restrict__ xz16,
           const float* __restrict__ Abuf,
           const float* __restrict__ Ibuf, const float* __restrict__ Dvec,
           __hip_bfloat16* __restrict__ ybf)
{
    const int blk = blockIdx.x;
    const int dblk = blk % 3, ch = (blk / 3) % NCH, b = blk / (3 * NCH);
    const int d = dblk * 256 + threadIdx.x;
    const int t0 = ch * TCH;
    const size_t brow = (size_t)(b * Lc + t0);

    __shared__ float bcs[TCH * 32];
    {
        const int row = threadIdx.x >> 3, c4 = (threadIdx.x & 7) * 4;
        *(float4*)&bcs[row * 32 + c4] =
            *(const float4*)(dtbc + (brow + row) * NDTBC + Dc + c4);
    }
    __syncthreads();

    float A[16], s[16];
    #pragma unroll
    for (int q = 0; q < 4; ++q)
        *(float4*)&A[q * 4] = *(const float4*)(Abuf + d * 16 + q * 4);
    const size_t g = (size_t)(b * NCH + ch) * Dc + d;
    #pragma unroll
    for (int q = 0; q < 4; ++q)
        *(float4*)&s[q * 4] = *(const float4*)(Ibuf + g * 16 + q * 4);
    const float Dd = Dvec[d];

    #pragma unroll 4
    for (int t = 0; t < TCH; ++t) {
        const float dt = dtbc[(brow + t) * NDTBC + d];   // pre-softplus'd
        const float x  = __bfloat162float(xsb[(brow + t) * Dc + d]);
        const float z  = __bfloat162float(xz16[(brow + t) * TWO_D + Dc + d]);
        float Bt[16], Ct[16];
        #pragma unroll
        for (int q = 0; q < 4; ++q) {
            *(float4*)&Bt[q * 4] = *(const float4*)&bcs[t * 32 + q * 4];
            *(float4*)&Ct[q * 4] = *(const float4*)&bcs[t * 32 + 16 + q * 4];
        }
        float yl = fmaf(Dd, x, 0.f);
        #pragma unroll
        for (int n = 0; n < 16; ++n) {
            const float dA = fexp2(dt * A[n]);
            s[n] = fmaf(s[n], dA, Bt[n] * x);
            yl = fmaf(s[n], Ct[n], yl);
        }
        ybf[(brow + t) * Dc + d] = __float2bfloat16(yl * siluf(z));
    }
}

extern "C" void kernel_launch(void* const* d_in, const int* in_sizes, int n_in,
                              void* d_out, int out_size, void* d_ws, size_t ws_size,
                              hipStream_t stream)
{
    const float* x      = (const float*)d_in[0];
    const float* state  = (const float*)d_in[1];
    const float* W_in   = (const float*)d_in[2];
    const float* conv_w = (const float*)d_in[3];
    const float* conv_b = (const float*)d_in[4];
    const float* W_x    = (const float*)d_in[5];
    const float* W_dt   = (const float*)d_in[6];
    const float* b_dt   = (const float*)d_in[7];
    const float* A_log  = (const float*)d_in[8];
    const float* Dvec   = (const float*)d_in[9];
    const float* W_out  = (const float*)d_in[10];
    float* out = (float*)d_out;

    // ---- workspace (~191 MB <= 253.75 verified; R19/R20 layout) ----
    char* wsb = (char*)d_ws;
    __hip_bfloat16* xz16 = (__hip_bfloat16*)wsb;     wsb += (size_t)M_TOT * TWO_D * 2;
    float* dtbc  = (float*)wsb;                      wsb += (size_t)M_TOT * NDTBC * 4;
    float* Sb    = (float*)wsb;                      wsb += (size_t)Bc * NCH * Dc * Nc * 4;
    float* dcend = (float*)wsb;                      wsb += (size_t)Bc * NCH * Dc * 4;
    __hip_bfloat16* xb  = (__hip_bfloat16*)wsb;      wsb += (size_t)M_TOT * Dc * 2;
    __hip_bfloat16* xsb = (__hip_bfloat16*)wsb;      wsb += (size_t)M_TOT * Dc * 2;
    float* Abuf = (float*)wsb;                       wsb += (size_t)Dc * Nc * 4;
    __hip_bfloat16* WinT  = (__hip_bfloat16*)wsb;    wsb += (size_t)1536 * Kd * 2;
    __hip_bfloat16* WcatT = (__hip_bfloat16*)wsb;    wsb += (size_t)NDTBC * Kd * 2;
    __hip_bfloat16* WoutT = (__hip_bfloat16*)wsb;    wsb += (size_t)768 * Kd * 2;
    float* Ib = Sb;                               // scanB in-place (verified)
    __hip_bfloat16* ybf = xb;                     // xb dead after in_proj

    // ---- prep (no memset; no templates) ----
    to_bf16_kernel<<<(M_TOT * Dc / 4 + 255) / 256, 256, 0, stream>>>(x, xb, M_TOT * Dc / 4);
    wtrans_tile<<<dim3(1536 / 32, Kd / 32), 256, 0, stream>>>(W_in, WinT, 1536);
    wtrans_tile<<<dim3(768 / 32, Kd / 32), 256, 0, stream>>>(W_dt, WcatT, 768);
    wtrans_tile<<<dim3(32 / 32, Kd / 32), 256, 0, stream>>>(W_x, WcatT + (size_t)768 * Kd, 32);
    wtrans_tile<<<dim3(768 / 32, Kd / 32), 256, 0, stream>>>(W_out, WoutT, 768);
    aprep_kernel<<<(Dc * Nc + 255) / 256, 256, 0, stream>>>(A_log, Abuf);

    // 1) in_proj fused N=1536, bf16 out (BK=64)
    gemm_bf16_b16<<<dim3(TWO_D / 128, M_TOT / 128), 256, 0, stream>>>(
        xb, WinT, TWO_D, xz16);
    // 2) conv + silu -> bf16 xsb
    conv_silu_kernel<<<((M_TOT / 8) * (Dc / 2) + 255) / 256, 256, 0, stream>>>(
        xz16, conv_w, conv_b, xsb);
    // 3) fused dt|BC: dtbc = xsb @ [W_dt|W_x|pad], N=896 (BK=64)
    gemm_bf16_f32<<<dim3(NDTBC / 128, M_TOT / 128), 256, 0, stream>>>(
        xsb, WcatT, NDTBC, dtbc);
    // 4) scan (NCH=128 reverted)
    scanA<<<Bc * NCH * 3, 256, 0, stream>>>(dtbc, xsb, Abuf, b_dt, Sb, dcend);
    scanB<<<(Bc * Dc * Nc) / 256, 256, 0, stream>>>(Sb, dcend, Abuf);
    scanC<<<Bc * NCH * 3, 256, 0, stream>>>(dtbc, xsb, xz16, Abuf, Ib, Dvec, ybf);
    // 5) out = y @ W_out (N=768, BK=64)
    gemm_bf16_f32<<<dim3(Dc / 128, M_TOT / 128), 256, 0, stream>>>(ybf, WoutT, Dc, out);
    // 6) state pass-through
    hipMemcpyAsync(out + (size_t)M_TOT * Dc, state,
                   (size_t)(Bc * Dc * Nc) * sizeof(float),
                   hipMemcpyDeviceToDevice, stream);
}

// Round 23
// 256.611 us; speedup vs baseline: 1.1525x; 1.0152x over previous
//
#include <hip/hip_runtime.h>
#include <hip/hip_bf16.h>
#include <cstdint>
#include <cstddef>

constexpr int Bc = 4, Lc = 4096, Dc = 768, Nc = 16;
constexpr int M_TOT = Bc * Lc;     // 16384
constexpr int NCH = 128;           // chunks per sequence
constexpr int TCH = Lc / NCH;      // 32
constexpr int Kd = 768;            // K of all GEMMs
constexpr int TWO_D = 1536;
constexpr int NDTBC = 896;         // fused [dt | B,C | pad] width (7*128)

typedef __attribute__((ext_vector_type(8))) short short8v;   // 8 bf16 (4 VGPRs)
typedef __attribute__((ext_vector_type(4))) float f32x4;     // MFMA acc

__device__ __forceinline__ float fexp2(float x) {
#if __has_builtin(__builtin_amdgcn_exp2f)
    return __builtin_amdgcn_exp2f(x);
#else
    return exp2f(x);
#endif
}
__device__ __forceinline__ float softplusf(float x) {
    return (x > 20.0f) ? x : __logf(1.0f + __expf(x));
}
__device__ __forceinline__ float siluf(float x) {
    return x / (1.0f + __expf(-x));
}
__device__ __forceinline__ float bf16lo(uint32_t v) {
    return __uint_as_float(v << 16);
}
__device__ __forceinline__ float bf16hi(uint32_t v) {
    return __uint_as_float(v & 0xffff0000u);
}
__device__ __forceinline__ float bf16s(const __hip_bfloat16* p) {
    return __uint_as_float((uint32_t)(*(const uint16_t*)p) << 16);
}

// XCD-aware tile swizzle (T1; grids 1536/896/768, all %8==0 -> bijective).
__device__ __forceinline__ void swizzled_tile(int& row0, int& col0)
{
    const int nwg = gridDim.x * gridDim.y;
    const int bid = blockIdx.y * gridDim.x + blockIdx.x;
    const int swz = (bid & 7) * (nwg >> 3) + (bid >> 3);
    row0 = (swz / gridDim.x) * 128;
    col0 = (swz % gridDim.x) * 128;
}

// ---------- bf16 MFMA GEMM, BK=64 + T2 swizzle, fp32 out (R22 HW-verified) ----------
__global__ __launch_bounds__(256)
void gemm_bf16_f32(const __hip_bfloat16* __restrict__ Ab,
                   const __hip_bfloat16* __restrict__ Wt,
                   int N, float* __restrict__ out0)
{
    __shared__ __hip_bfloat16 Asm[128 * 64];
    __shared__ __hip_bfloat16 Bsm[128 * 64];
    const int tid = threadIdx.x;
    const int w = tid >> 6, lane = tid & 63;
    const int lr = lane & 15, lc = lane >> 4;
    int row0, col0;
    swizzled_tile(row0, col0);
    const int wrow = (w >> 1) * 64, wcol = (w & 1) * 64;

    const int grow = lane >> 3;
    const int gcol = 8 * ((lane & 7) ^ (lane >> 3));
    const int rsw = (lr & 7) << 4;

    f32x4 acc[4][4] = {};

    const int KT = Kd / 64;
    for (int kt = 0; kt < KT; ++kt) {
        if (kt) __syncthreads();
        #pragma unroll
        for (int i = 0; i < 4; ++i) {
            const int g = w * 4 + i;
            const __hip_bfloat16* asrc =
                Ab + (size_t)(row0 + g * 8 + grow) * Kd + kt * 64 + gcol;
            const __hip_bfloat16* bsrc =
                Wt + (size_t)(col0 + g * 8 + grow) * Kd + kt * 64 + gcol;
            __builtin_amdgcn_global_load_lds(
                (const __attribute__((address_space(1))) void*)asrc,
                (__attribute__((address_space(3))) void*)(Asm + g * 512), 16, 0, 0);
            __builtin_amdgcn_global_load_lds(
                (const __attribute__((address_space(1))) void*)bsrc,
                (__attribute__((address_space(3))) void*)(Bsm + g * 512), 16, 0, 0);
        }
        asm volatile("s_waitcnt vmcnt(0)" ::: "memory");
        __syncthreads();

        #pragma unroll
        for (int kk = 0; kk < 2; ++kk) {
            const int rq = (kk * 64 + lc * 16) ^ rsw;
            short8v a[4], b[4];
            #pragma unroll
            for (int m = 0; m < 4; ++m)
                a[m] = *(const short8v*)((char*)Asm + (wrow + m * 16 + lr) * 128 + rq);
            #pragma unroll
            for (int nf = 0; nf < 4; ++nf)
                b[nf] = *(const short8v*)((char*)Bsm + (wcol + nf * 16 + lr) * 128 + rq);
            #pragma unroll
            for (int m = 0; m < 4; ++m)
                #pragma unroll
                for (int nf = 0; nf < 4; ++nf)
                    acc[m][nf] = __builtin_amdgcn_mfma_f32_16x16x32_bf16(
                        a[m], b[nf], acc[m][nf], 0, 0, 0);
        }
    }

    #pragma unroll
    for (int m = 0; m < 4; ++m)
        #pragma unroll
        for (int nf = 0; nf < 4; ++nf)
            #pragma unroll
            for (int j = 0; j < 4; ++j) {
                const int rg = row0 + wrow + m * 16 + lc * 4 + j;
                const int cg = col0 + wcol + nf * 16 + lr;
                out0[(size_t)rg * N + cg] = acc[m][nf][j];
            }
}

// ---------- same BK=64 body, bf16 out (SEPARATE non-template kernel; R22-verified) ----------
__global__ __launch_bounds__(256)
void gemm_bf16_b16(const __hip_bfloat16* __restrict__ Ab,
                   const __hip_bfloat16* __restrict__ Wt,
                   int N, __hip_bfloat16* __restrict__ outb)
{
    __shared__ __hip_bfloat16 Asm[128 * 64];
    __shared__ __hip_bfloat16 Bsm[128 * 64];
    const int tid = threadIdx.x;
    const int w = tid >> 6, lane = tid & 63;
    const int lr = lane & 15, lc = lane >> 4;
    int row0, col0;
    swizzled_tile(row0, col0);
    const int wrow = (w >> 1) * 64, wcol = (w & 1) * 64;

    const int grow = lane >> 3;
    const int gcol = 8 * ((lane & 7) ^ (lane >> 3));
    const int rsw = (lr & 7) << 4;

    f32x4 acc[4][4] = {};

    const int KT = Kd / 64;
    for (int kt = 0; kt < KT; ++kt) {
        if (kt) __syncthreads();
        #pragma unroll
        for (int i = 0; i < 4; ++i) {
            const int g = w * 4 + i;
            const __hip_bfloat16* asrc =
                Ab + (size_t)(row0 + g * 8 + grow) * Kd + kt * 64 + gcol;
            const __hip_bfloat16* bsrc =
                Wt + (size_t)(col0 + g * 8 + grow) * Kd + kt * 64 + gcol;
            __builtin_amdgcn_global_load_lds(
                (const __attribute__((address_space(1))) void*)asrc,
                (__attribute__((address_space(3))) void*)(Asm + g * 512), 16, 0, 0);
            __builtin_amdgcn_global_load_lds(
                (const __attribute__((address_space(1))) void*)bsrc,
                (__attribute__((address_space(3))) void*)(Bsm + g * 512), 16, 0, 0);
        }
        asm volatile("s_waitcnt vmcnt(0)" ::: "memory");
        __syncthreads();

        #pragma unroll
        for (int kk = 0; kk < 2; ++kk) {
            const int rq = (kk * 64 + lc * 16) ^ rsw;
            short8v a[4], b[4];
            #pragma unroll
            for (int m = 0; m < 4; ++m)
                a[m] = *(const short8v*)((char*)Asm + (wrow + m * 16 + lr) * 128 + rq);
            #pragma unroll
            for (int nf = 0; nf < 4; ++nf)
                b[nf] = *(const short8v*)((char*)Bsm + (wcol + nf * 16 + lr) * 128 + rq);
            #pragma unroll
            for (int m = 0; m < 4; ++m)
                #pragma unroll
                for (int nf = 0; nf < 4; ++nf)
                    acc[m][nf] = __builtin_amdgcn_mfma_f32_16x16x32_bf16(
                        a[m], b[nf], acc[m][nf], 0, 0, 0);
        }
    }

    #pragma unroll
    for (int m = 0; m < 4; ++m)
        #pragma unroll
        for (int nf = 0; nf < 4; ++nf)
            #pragma unroll
            for (int j = 0; j < 4; ++j) {
                const int rg = row0 + wrow + m * 16 + lc * 4 + j;
                const int cg = col0 + wcol + nf * 16 + lr;
                outb[(size_t)rg * N + cg] = __float2bfloat16(acc[m][nf][j]);
            }
}

// ---------------- prep kernels (HW-verified) ----------------
__global__ __launch_bounds__(256)
void to_bf16_kernel(const float* __restrict__ src, __hip_bfloat16* __restrict__ dst, int n4)
{
    const int i = blockIdx.x * 256 + threadIdx.x;
    if (i >= n4) return;
    const float4 v = ((const float4*)src)[i];
    dst[i * 4 + 0] = __float2bfloat16(v.x);
    dst[i * 4 + 1] = __float2bfloat16(v.y);
    dst[i * 4 + 2] = __float2bfloat16(v.z);
    dst[i * 4 + 3] = __float2bfloat16(v.w);
}

__global__ __launch_bounds__(256)
void wtrans_tile(const float* __restrict__ src, __hip_bfloat16* __restrict__ dst, int N)
{
    __shared__ float tile[32][33];
    const int n0 = blockIdx.x * 32, k0 = blockIdx.y * 32;
    const int tx = threadIdx.x & 31, ty = threadIdx.x >> 5;
    #pragma unroll
    for (int r = 0; r < 4; ++r) {
        const int k = ty + r * 8;
        tile[k][tx] = src[(size_t)(k0 + k) * N + n0 + tx];
    }
    __syncthreads();
    #pragma unroll
    for (int r = 0; r < 4; ++r) {
        const int n = ty + r * 8;
        dst[(size_t)(n0 + n) * Kd + k0 + tx] = __float2bfloat16(tile[tx][n]);
    }
}

__global__ __launch_bounds__(256)
void aprep_kernel(const float* __restrict__ A_log, float* __restrict__ Abuf)
{
    const int i = blockIdx.x * 256 + threadIdx.x;
    if (i < Dc * Nc) Abuf[i] = -expf(A_log[i]) * 1.4426950408889634f;
}

// ---------------- t-blocked conv + silu (R20, HW-verified) ----------------
__global__ __launch_bounds__(256)
void conv_silu_kernel(const __hip_bfloat16* __restrict__ xz16, const float* __restrict__ cw,
                      const float* __restrict__ cb, __hip_bfloat16* __restrict__ xsb)
{
    const int ND2 = Dc / 2;
    const int idx = blockIdx.x * 256 + threadIdx.x;
    if (idx >= (M_TOT / 8) * ND2) return;
    const int d0 = (idx % ND2) * 2;
    const int r8 = idx / ND2;
    const int tb = r8 & (Lc / 8 - 1);
    const int b = r8 / (Lc / 8);
    const int t0 = tb * 8;
    const size_t rbase = (size_t)(b * Lc + t0);

    const float w00 = cw[d0 * 4 + 0], w01 = cw[d0 * 4 + 1],
                w02 = cw[d0 * 4 + 2], w03 = cw[d0 * 4 + 3];
    const float w10 = cw[d0 * 4 + 4], w11 = cw[d0 * 4 + 5],
                w12 = cw[d0 * 4 + 6], w13 = cw[d0 * 4 + 7];
    const float bias0 = cb[d0], bias1 = cb[d0 + 1];

    float a3 = 0.f, a2 = 0.f, a1 = 0.f;
    float b3 = 0.f, b2 = 0.f, b1 = 0.f;
    if (t0 >= 3) {
        const uint32_t v3 = *(const uint32_t*)(xz16 + (rbase - 3) * TWO_D + d0);
        const uint32_t v2 = *(const uint32_t*)(xz16 + (rbase - 2) * TWO_D + d0);
        const uint32_t v1 = *(const uint32_t*)(xz16 + (rbase - 1) * TWO_D + d0);
        a3 = bf16lo(v3); b3 = bf16hi(v3);
        a2 = bf16lo(v2); b2 = bf16hi(v2);
        a1 = bf16lo(v1); b1 = bf16hi(v1);
    }
    #pragma unroll
    for (int tt = 0; tt < 8; ++tt) {
        const uint32_t v0 = *(const uint32_t*)(xz16 + (rbase + tt) * TWO_D + d0);
        const float x0a = bf16lo(v0), x0b = bf16hi(v0);
        const float ra = siluf(fmaf(w03, x0a, fmaf(w02, a1, fmaf(w01, a2, fmaf(w00, a3, bias0)))));
        const float rb = siluf(fmaf(w13, x0b, fmaf(w12, b1, fmaf(w11, b2, fmaf(w10, b3, bias1)))));
        __hip_bfloat16 o2[2] = { __float2bfloat16(ra), __float2bfloat16(rb) };
        *(uint32_t*)(xsb + (rbase + tt) * Dc + d0) = *(const uint32_t*)o2;
        a3 = a2; a2 = a1; a1 = x0a;
        b3 = b2; b2 = b1; b1 = x0b;
    }
}

// ---------------- chunked scan, bf16 dtbc (dt|B,C all bf16, stride 896) ----------------
// Phase A: recurrence; caches softplus(dt) in place as bf16 (same owner-thread
// read-then-write discipline verified in R20; B|C staging cols disjoint).
__global__ __launch_bounds__(256)
void scanA(__hip_bfloat16* __restrict__ dtbc, const __hip_bfloat16* __restrict__ xsb,
           const float* __restrict__ Abuf, const float* __restrict__ bdt,
           float* __restrict__ S, float* __restrict__ dcend)
{
    const int blk = blockIdx.x;
    const int dblk = blk % 3, ch = (blk / 3) % NCH, b = blk / (3 * NCH);
    const int d = dblk * 256 + threadIdx.x;
    const int t0 = ch * TCH;
    const size_t brow = (size_t)(b * Lc + t0);

    __shared__ float bcs[TCH * 32];   // fp32 decode of bf16 B|C tile
    {
        const int row = threadIdx.x >> 3, c4 = (threadIdx.x & 7) * 4;
        const uint2 v = *(const uint2*)(dtbc + (brow + row) * NDTBC + Dc + c4);
        bcs[row * 32 + c4 + 0] = bf16lo(v.x);
        bcs[row * 32 + c4 + 1] = bf16hi(v.x);
        bcs[row * 32 + c4 + 2] = bf16lo(v.y);
        bcs[row * 32 + c4 + 3] = bf16hi(v.y);
    }
    __syncthreads();

    float A[16];
    #pragma unroll
    for (int q = 0; q < 4; ++q)
        *(float4*)&A[q * 4] = *(const float4*)(Abuf + d * 16 + q * 4);
    const float bd = bdt[d];

    float s[16];
    #pragma unroll
    for (int n = 0; n < 16; ++n) s[n] = 0.f;

    float dc = 0.f;
    #pragma unroll 4
    for (int t = 0; t < TCH; ++t) {
        const size_t doff = (brow + t) * NDTBC + d;
        const float dt = softplusf(bf16s(dtbc + doff) + bd);
        dtbc[doff] = __float2bfloat16(dt);             // cache for scanC
        const float x = __bfloat162float(xsb[(brow + t) * Dc + d]);
        dc += dt;
        float Bt[16];
        #pragma unroll
        for (int q = 0; q < 4; ++q)
            *(float4*)&Bt[q * 4] = *(const float4*)&bcs[t * 32 + q * 4];
        #pragma unroll
        for (int n = 0; n < 16; ++n) {
            const float dA = fexp2(dt * A[n]);
            s[n] = fmaf(s[n], dA, Bt[n] * x);
        }
    }
    const size_t g = (size_t)(b * NCH + ch) * Dc + d;
    #pragma unroll
    for (int n = 0; n < 16; ++n) S[g * 16 + n] = s[n];
    dcend[g] = dc;
}

__global__ __launch_bounds__(256)
void scanB(float* __restrict__ S_io, const float* __restrict__ dcend,
           const float* __restrict__ Abuf)
{
    const int tid = blockIdx.x * 256 + threadIdx.x;
    const int n = tid & 15;
    const int d = (tid >> 4) % Dc;
    const int b = tid / (16 * Dc);
    const float An = Abuf[d * 16 + n];
    float s = 0.f;
    for (int ch = 0; ch < NCH; ++ch) {
        const size_t g = (size_t)(b * NCH + ch) * Dc + d;
        const float sv = S_io[g * 16 + n];
        const float p  = fexp2(dcend[g] * An);
        S_io[g * 16 + n] = s;
        s = fmaf(s, p, sv);
    }
}

__global__ __launch_bounds__(256)
void scanC(const __hip_bfloat16* __restrict__ dtbc, const __hip_bfloat16* __restrict__ xsb,
           const __hip_bfloat16* __restrict__ xz16,
           const float* __restrict__ Abuf,
           const float* __restrict__ Ibuf, const float* __restrict__ Dvec,
           __hip_bfloat16* __restrict__ ybf)
{
    const int blk = blockIdx.x;
    const int dblk = blk % 3, ch = (blk / 3) % NCH, b = blk / (3 * NCH);
    const int d = dblk * 256 + threadIdx.x;
    const int t0 = ch * TCH;
    const size_t brow = (size_t)(b * Lc + t0);

    __shared__ float bcs[TCH * 32];
    {
        const int row = threadIdx.x >> 3, c4 = (threadIdx.x & 7) * 4;
        const uint2 v = *(const uint2*)(dtbc + (brow + row) * NDTBC + Dc + c4);
        bcs[row * 32 + c4 + 0] = bf16lo(v.x);
        bcs[row * 32 + c4 + 1] = bf16hi(v.x);
        bcs[row * 32 + c4 + 2] = bf16lo(v.y);
        bcs[row * 32 + c4 + 3] = bf16hi(v.y);
    }
    __syncthreads();

    float A[16], s[16];
    #pragma unroll
    for (int q = 0; q < 4; ++q)
        *(float4*)&A[q * 4] = *(const float4*)(Abuf + d * 16 + q * 4);
    const size_t g = (size_t)(b * NCH + ch) * Dc + d;
    #pragma unroll
    for (int q = 0; q < 4; ++q)
        *(float4*)&s[q * 4] = *(const float4*)(Ibuf + g * 16 + q * 4);
    const float Dd = Dvec[d];

    #pragma unroll 4
    for (int t = 0; t < TCH; ++t) {
        const float dt = bf16s(dtbc + (brow + t) * NDTBC + d);   // pre-softplus'd
        const float x  = __bfloat162float(xsb[(brow + t) * Dc + d]);
        const float z  = __bfloat162float(xz16[(brow + t) * TWO_D + Dc + d]);
        float Bt[16], Ct[16];
        #pragma unroll
        for (int q = 0; q < 4; ++q) {
            *(float4*)&Bt[q * 4] = *(const float4*)&bcs[t * 32 + q * 4];
            *(float4*)&Ct[q * 4] = *(const float4*)&bcs[t * 32 + 16 + q * 4];
        }
        float yl = fmaf(Dd, x, 0.f);
        #pragma unroll
        for (int n = 0; n < 16; ++n) {
            const float dA = fexp2(dt * A[n]);
            s[n] = fmaf(s[n], dA, Bt[n] * x);
            yl = fmaf(s[n], Ct[n], yl);
        }
        ybf[(brow + t) * Dc + d] = __float2bfloat16(yl * siluf(z));
    }
}

extern "C" void kernel_launch(void* const* d_in, const int* in_sizes, int n_in,
                              void* d_out, int out_size, void* d_ws, size_t ws_size,
                              hipStream_t stream)
{
    const float* x      = (const float*)d_in[0];
    const float* state  = (const float*)d_in[1];
    const float* W_in   = (const float*)d_in[2];
    const float* conv_w = (const float*)d_in[3];
    const float* conv_b = (const float*)d_in[4];
    const float* W_x    = (const float*)d_in[5];
    const float* W_dt   = (const float*)d_in[6];
    const float* b_dt   = (const float*)d_in[7];
    const float* A_log  = (const float*)d_in[8];
    const float* Dvec   = (const float*)d_in[9];
    const float* W_out  = (const float*)d_in[10];
    float* out = (float*)d_out;

    // ---- workspace (~163 MB <= 253.75 verified) ----
    char* wsb = (char*)d_ws;
    __hip_bfloat16* xz16 = (__hip_bfloat16*)wsb;     wsb += (size_t)M_TOT * TWO_D * 2;
    __hip_bfloat16* dtbc = (__hip_bfloat16*)wsb;     wsb += (size_t)M_TOT * NDTBC * 2;  // [dt | B,C | pad] bf16
    float* Sb    = (float*)wsb;                      wsb += (size_t)Bc * NCH * Dc * Nc * 4;
    float* dcend = (float*)wsb;                      wsb += (size_t)Bc * NCH * Dc * 4;
    __hip_bfloat16* xb  = (__hip_bfloat16*)wsb;      wsb += (size_t)M_TOT * Dc * 2;
    __hip_bfloat16* xsb = (__hip_bfloat16*)wsb;      wsb += (size_t)M_TOT * Dc * 2;
    float* Abuf = (float*)wsb;                       wsb += (size_t)Dc * Nc * 4;
    __hip_bfloat16* WinT  = (__hip_bfloat16*)wsb;    wsb += (size_t)1536 * Kd * 2;
    __hip_bfloat16* WcatT = (__hip_bfloat16*)wsb;    wsb += (size_t)NDTBC * Kd * 2;
    __hip_bfloat16* WoutT = (__hip_bfloat16*)wsb;    wsb += (size_t)768 * Kd * 2;
    float* Ib = Sb;                               // scanB in-place (verified)
    __hip_bfloat16* ybf = xb;                     // xb dead after in_proj

    // ---- prep (no memset; no templates) ----
    to_bf16_kernel<<<(M_TOT * Dc / 4 + 255) / 256, 256, 0, stream>>>(x, xb, M_TOT * Dc / 4);
    wtrans_tile<<<dim3(1536 / 32, Kd / 32), 256, 0, stream>>>(W_in, WinT, 1536);
    wtrans_tile<<<dim3(768 / 32, Kd / 32), 256, 0, stream>>>(W_dt, WcatT, 768);
    wtrans_tile<<<dim3(32 / 32, Kd / 32), 256, 0, stream>>>(W_x, WcatT + (size_t)768 * Kd, 32);
    wtrans_tile<<<dim3(768 / 32, Kd / 32), 256, 0, stream>>>(W_out, WoutT, 768);
    aprep_kernel<<<(Dc * Nc + 255) / 256, 256, 0, stream>>>(A_log, Abuf);

    // 1) in_proj fused N=1536, bf16 out (BK=64)
    gemm_bf16_b16<<<dim3(TWO_D / 128, M_TOT / 128), 256, 0, stream>>>(
        xb, WinT, TWO_D, xz16);
    // 2) conv + silu -> bf16 xsb
    conv_silu_kernel<<<((M_TOT / 8) * (Dc / 2) + 255) / 256, 256, 0, stream>>>(
        xz16, conv_w, conv_b, xsb);
    // 3) fused dt|BC: dtbc = xsb @ [W_dt|W_x|pad], N=896, bf16 out
    gemm_bf16_b16<<<dim3(NDTBC / 128, M_TOT / 128), 256, 0, stream>>>(
        xsb, WcatT, NDTBC, dtbc);
    // 4) scan (bf16 dt/B/C)
    scanA<<<Bc * NCH * 3, 256, 0, stream>>>(dtbc, xsb, Abuf, b_dt, Sb, dcend);
    scanB<<<(Bc * Dc * Nc) / 256, 256, 0, stream>>>(Sb, dcend, Abuf);
    scanC<<<Bc * NCH * 3, 256, 0, stream>>>(dtbc, xsb, xz16, Abuf, Ib, Dvec, ybf);
    // 5) out = y @ W_out (N=768, fp32 out)
    gemm_bf16_f32<<<dim3(Dc / 128, M_TOT / 128), 256, 0, stream>>>(ybf, WoutT, Dc, out);
    // 6) state pass-through
    hipMemcpyAsync(out + (size_t)M_TOT * Dc, state,
                   (size_t)(Bc * Dc * Nc) * sizeof(float),
                   hipMemcpyDeviceToDevice, stream);
}

// Round 24
// 239.913 us; speedup vs baseline: 1.2327x; 1.0696x over previous
//
#include <hip/hip_runtime.h>
#include <hip/hip_bf16.h>
#include <cstdint>
#include <cstddef>

constexpr int Bc = 4, Lc = 4096, Dc = 768, Nc = 16;
constexpr int M_TOT = Bc * Lc;     // 16384
constexpr int NCH = 128;           // chunks per sequence
constexpr int TCH = Lc / NCH;      // 32
constexpr int Kd = 768;            // K of all GEMMs
constexpr int TWO_D = 1536;
constexpr int NDTBC = 896;         // fused [dt | B,C | pad] width (7*128)

typedef __attribute__((ext_vector_type(8))) short short8v;   // 8 bf16 (4 VGPRs)
typedef __attribute__((ext_vector_type(4))) float f32x4;     // MFMA acc

__device__ __forceinline__ float fexp2(float x) {
#if __has_builtin(__builtin_amdgcn_exp2f)
    return __builtin_amdgcn_exp2f(x);
#else
    return exp2f(x);
#endif
}
__device__ __forceinline__ float softplusf(float x) {
    return (x > 20.0f) ? x : __logf(1.0f + __expf(x));
}
__device__ __forceinline__ float siluf(float x) {
    return x / (1.0f + __expf(-x));
}
__device__ __forceinline__ float bf16lo(uint32_t v) {
    return __uint_as_float(v << 16);
}
__device__ __forceinline__ float bf16hi(uint32_t v) {
    return __uint_as_float(v & 0xffff0000u);
}
__device__ __forceinline__ float bf16s(const __hip_bfloat16* p) {
    return __uint_as_float((uint32_t)(*(const uint16_t*)p) << 16);
}

// XCD-aware tile swizzle (T1; grids 1536/896/768, all %8==0 -> bijective).
__device__ __forceinline__ void swizzled_tile(int& row0, int& col0)
{
    const int nwg = gridDim.x * gridDim.y;
    const int bid = blockIdx.y * gridDim.x + blockIdx.x;
    const int swz = (bid & 7) * (nwg >> 3) + (bid >> 3);
    row0 = (swz / gridDim.x) * 128;
    col0 = (swz % gridDim.x) * 128;
}

// ---------- bf16 MFMA GEMM, BK=64 + T2 swizzle, fp32 out (R22 HW-verified) ----------
__global__ __launch_bounds__(256)
void gemm_bf16_f32(const __hip_bfloat16* __restrict__ Ab,
                   const __hip_bfloat16* __restrict__ Wt,
                   int N, float* __restrict__ out0)
{
    __shared__ __hip_bfloat16 Asm[128 * 64];
    __shared__ __hip_bfloat16 Bsm[128 * 64];
    const int tid = threadIdx.x;
    const int w = tid >> 6, lane = tid & 63;
    const int lr = lane & 15, lc = lane >> 4;
    int row0, col0;
    swizzled_tile(row0, col0);
    const int wrow = (w >> 1) * 64, wcol = (w & 1) * 64;

    const int grow = lane >> 3;
    const int gcol = 8 * ((lane & 7) ^ (lane >> 3));
    const int rsw = (lr & 7) << 4;

    f32x4 acc[4][4] = {};

    const int KT = Kd / 64;
    for (int kt = 0; kt < KT; ++kt) {
        if (kt) __syncthreads();
        #pragma unroll
        for (int i = 0; i < 4; ++i) {
            const int g = w * 4 + i;
            const __hip_bfloat16* asrc =
                Ab + (size_t)(row0 + g * 8 + grow) * Kd + kt * 64 + gcol;
            const __hip_bfloat16* bsrc =
                Wt + (size_t)(col0 + g * 8 + grow) * Kd + kt * 64 + gcol;
            __builtin_amdgcn_global_load_lds(
                (const __attribute__((address_space(1))) void*)asrc,
                (__attribute__((address_space(3))) void*)(Asm + g * 512), 16, 0, 0);
            __builtin_amdgcn_global_load_lds(
                (const __attribute__((address_space(1))) void*)bsrc,
                (__attribute__((address_space(3))) void*)(Bsm + g * 512), 16, 0, 0);
        }
        asm volatile("s_waitcnt vmcnt(0)" ::: "memory");
        __syncthreads();

        #pragma unroll
        for (int kk = 0; kk < 2; ++kk) {
            const int rq = (kk * 64 + lc * 16) ^ rsw;
            short8v a[4], b[4];
            #pragma unroll
            for (int m = 0; m < 4; ++m)
                a[m] = *(const short8v*)((char*)Asm + (wrow + m * 16 + lr) * 128 + rq);
            #pragma unroll
            for (int nf = 0; nf < 4; ++nf)
                b[nf] = *(const short8v*)((char*)Bsm + (wcol + nf * 16 + lr) * 128 + rq);
            #pragma unroll
            for (int m = 0; m < 4; ++m)
                #pragma unroll
                for (int nf = 0; nf < 4; ++nf)
                    acc[m][nf] = __builtin_amdgcn_mfma_f32_16x16x32_bf16(
                        a[m], b[nf], acc[m][nf], 0, 0, 0);
        }
    }

    #pragma unroll
    for (int m = 0; m < 4; ++m)
        #pragma unroll
        for (int nf = 0; nf < 4; ++nf)
            #pragma unroll
            for (int j = 0; j < 4; ++j) {
                const int rg = row0 + wrow + m * 16 + lc * 4 + j;
                const int cg = col0 + wcol + nf * 16 + lr;
                out0[(size_t)rg * N + cg] = acc[m][nf][j];
            }
}

// ---------- same BK=64 body, bf16 out (SEPARATE non-template kernel; R22-verified) ----------
__global__ __launch_bounds__(256)
void gemm_bf16_b16(const __hip_bfloat16* __restrict__ Ab,
                   const __hip_bfloat16* __restrict__ Wt,
                   int N, __hip_bfloat16* __restrict__ outb)
{
    __shared__ __hip_bfloat16 Asm[128 * 64];
    __shared__ __hip_bfloat16 Bsm[128 * 64];
    const int tid = threadIdx.x;
    const int w = tid >> 6, lane = tid & 63;
    const int lr = lane & 15, lc = lane >> 4;
    int row0, col0;
    swizzled_tile(row0, col0);
    const int wrow = (w >> 1) * 64, wcol = (w & 1) * 64;

    const int grow = lane >> 3;
    const int gcol = 8 * ((lane & 7) ^ (lane >> 3));
    const int rsw = (lr & 7) << 4;

    f32x4 acc[4][4] = {};

    const int KT = Kd / 64;
    for (int kt = 0; kt < KT; ++kt) {
        if (kt) __syncthreads();
        #pragma unroll
        for (int i = 0; i < 4; ++i) {
            const int g = w * 4 + i;
            const __hip_bfloat16* asrc =
                Ab + (size_t)(row0 + g * 8 + grow) * Kd + kt * 64 + gcol;
            const __hip_bfloat16* bsrc =
                Wt + (size_t)(col0 + g * 8 + grow) * Kd + kt * 64 + gcol;
            __builtin_amdgcn_global_load_lds(
                (const __attribute__((address_space(1))) void*)asrc,
                (__attribute__((address_space(3))) void*)(Asm + g * 512), 16, 0, 0);
            __builtin_amdgcn_global_load_lds(
                (const __attribute__((address_space(1))) void*)bsrc,
                (__attribute__((address_space(3))) void*)(Bsm + g * 512), 16, 0, 0);
        }
        asm volatile("s_waitcnt vmcnt(0)" ::: "memory");
        __syncthreads();

        #pragma unroll
        for (int kk = 0; kk < 2; ++kk) {
            const int rq = (kk * 64 + lc * 16) ^ rsw;
            short8v a[4], b[4];
            #pragma unroll
            for (int m = 0; m < 4; ++m)
                a[m] = *(const short8v*)((char*)Asm + (wrow + m * 16 + lr) * 128 + rq);
            #pragma unroll
            for (int nf = 0; nf < 4; ++nf)
                b[nf] = *(const short8v*)((char*)Bsm + (wcol + nf * 16 + lr) * 128 + rq);
            #pragma unroll
            for (int m = 0; m < 4; ++m)
                #pragma unroll
                for (int nf = 0; nf < 4; ++nf)
                    acc[m][nf] = __builtin_amdgcn_mfma_f32_16x16x32_bf16(
                        a[m], b[nf], acc[m][nf], 0, 0, 0);
        }
    }

    #pragma unroll
    for (int m = 0; m < 4; ++m)
        #pragma unroll
        for (int nf = 0; nf < 4; ++nf)
            #pragma unroll
            for (int j = 0; j < 4; ++j) {
                const int rg = row0 + wrow + m * 16 + lc * 4 + j;
                const int cg = col0 + wcol + nf * 16 + lr;
                outb[(size_t)rg * N + cg] = __float2bfloat16(acc[m][nf][j]);
            }
}

// ---------------- prep kernels ----------------
__global__ __launch_bounds__(256)
void to_bf16_kernel(const float* __restrict__ src, __hip_bfloat16* __restrict__ dst, int n4)
{
    const int i = blockIdx.x * 256 + threadIdx.x;
    if (i >= n4) return;
    const float4 v = ((const float4*)src)[i];
    dst[i * 4 + 0] = __float2bfloat16(v.x);
    dst[i * 4 + 1] = __float2bfloat16(v.y);
    dst[i * 4 + 2] = __float2bfloat16(v.z);
    dst[i * 4 + 3] = __float2bfloat16(v.w);
}

// ALL weight transposes in ONE dispatch (R19-verified tile body; branchy map).
// Tiles: W_in 48x24=1152 | W_dt 24x24=576 | W_x 1x24=24 | W_out 24x24=576 = 2328.
__global__ __launch_bounds__(256)
void wtrans_all(const float* __restrict__ Win, const float* __restrict__ Wdt,
                const float* __restrict__ Wx, const float* __restrict__ Wout,
                __hip_bfloat16* __restrict__ WinT, __hip_bfloat16* __restrict__ WcatT,
                __hip_bfloat16* __restrict__ WoutT)
{
    const int blk = blockIdx.x;
    const float* src;
    __hip_bfloat16* dst;
    int N, n0, k0;
    if (blk < 1152)      { const int b = blk;        src = Win;  dst = WinT;  N = 1536; n0 = (b % 48) * 32; k0 = (b / 48) * 32; }
    else if (blk < 1728) { const int b = blk - 1152; src = Wdt;  dst = WcatT; N = 768;  n0 = (b % 24) * 32; k0 = (b / 24) * 32; }
    else if (blk < 1752) { const int b = blk - 1728; src = Wx;   dst = WcatT + (size_t)768 * Kd; N = 32; n0 = 0; k0 = b * 32; }
    else                 { const int b = blk - 1752; src = Wout; dst = WoutT; N = 768;  n0 = (b % 24) * 32; k0 = (b / 24) * 32; }

    __shared__ float tile[32][33];
    const int tx = threadIdx.x & 31, ty = threadIdx.x >> 5;
    #pragma unroll
    for (int r = 0; r < 4; ++r) {
        const int k = ty + r * 8;
        tile[k][tx] = src[(size_t)(k0 + k) * N + n0 + tx];
    }
    __syncthreads();
    #pragma unroll
    for (int r = 0; r < 4; ++r) {
        const int n = ty + r * 8;
        dst[(size_t)(n0 + n) * Kd + k0 + tx] = __float2bfloat16(tile[tx][n]);
    }
}

__global__ __launch_bounds__(256)
void aprep_kernel(const float* __restrict__ A_log, float* __restrict__ Abuf)
{
    const int i = blockIdx.x * 256 + threadIdx.x;
    if (i < Dc * Nc) Abuf[i] = -expf(A_log[i]) * 1.4426950408889634f;
}

// ---------------- t-blocked conv + silu (R20, HW-verified) ----------------
__global__ __launch_bounds__(256)
void conv_silu_kernel(const __hip_bfloat16* __restrict__ xz16, const float* __restrict__ cw,
                      const float* __restrict__ cb, __hip_bfloat16* __restrict__ xsb)
{
    const int ND2 = Dc / 2;
    const int idx = blockIdx.x * 256 + threadIdx.x;
    if (idx >= (M_TOT / 8) * ND2) return;
    const int d0 = (idx % ND2) * 2;
    const int r8 = idx / ND2;
    const int tb = r8 & (Lc / 8 - 1);
    const int b = r8 / (Lc / 8);
    const int t0 = tb * 8;
    const size_t rbase = (size_t)(b * Lc + t0);

    const float w00 = cw[d0 * 4 + 0], w01 = cw[d0 * 4 + 1],
                w02 = cw[d0 * 4 + 2], w03 = cw[d0 * 4 + 3];
    const float w10 = cw[d0 * 4 + 4], w11 = cw[d0 * 4 + 5],
                w12 = cw[d0 * 4 + 6], w13 = cw[d0 * 4 + 7];
    const float bias0 = cb[d0], bias1 = cb[d0 + 1];

    float a3 = 0.f, a2 = 0.f, a1 = 0.f;
    float b3 = 0.f, b2 = 0.f, b1 = 0.f;
    if (t0 >= 3) {
        const uint32_t v3 = *(const uint32_t*)(xz16 + (rbase - 3) * TWO_D + d0);
        const uint32_t v2 = *(const uint32_t*)(xz16 + (rbase - 2) * TWO_D + d0);
        const uint32_t v1 = *(const uint32_t*)(xz16 + (rbase - 1) * TWO_D + d0);
        a3 = bf16lo(v3); b3 = bf16hi(v3);
        a2 = bf16lo(v2); b2 = bf16hi(v2);
        a1 = bf16lo(v1); b1 = bf16hi(v1);
    }
    #pragma unroll
    for (int tt = 0; tt < 8; ++tt) {
        const uint32_t v0 = *(const uint32_t*)(xz16 + (rbase + tt) * TWO_D + d0);
        const float x0a = bf16lo(v0), x0b = bf16hi(v0);
        const float ra = siluf(fmaf(w03, x0a, fmaf(w02, a1, fmaf(w01, a2, fmaf(w00, a3, bias0)))));
        const float rb = siluf(fmaf(w13, x0b, fmaf(w12, b1, fmaf(w11, b2, fmaf(w10, b3, bias1)))));
        __hip_bfloat16 o2[2] = { __float2bfloat16(ra), __float2bfloat16(rb) };
        *(uint32_t*)(xsb + (rbase + tt) * Dc + d0) = *(const uint32_t*)o2;
        a3 = a2; a2 = a1; a1 = x0a;
        b3 = b2; b2 = b1; b1 = x0b;
    }
}

// ---------------- chunked scan, bf16 dtbc + bf16 S/I ----------------
__global__ __launch_bounds__(256)
void scanA(__hip_bfloat16* __restrict__ dtbc, const __hip_bfloat16* __restrict__ xsb,
           const float* __restrict__ Abuf, const float* __restrict__ bdt,
           __hip_bfloat16* __restrict__ S, float* __restrict__ dcend)
{
    const int blk = blockIdx.x;
    const int dblk = blk % 3, ch = (blk / 3) % NCH, b = blk / (3 * NCH);
    const int d = dblk * 256 + threadIdx.x;
    const int t0 = ch * TCH;
    const size_t brow = (size_t)(b * Lc + t0);

    __shared__ float bcs[TCH * 32];
    {
        const int row = threadIdx.x >> 3, c4 = (threadIdx.x & 7) * 4;
        const uint2 v = *(const uint2*)(dtbc + (brow + row) * NDTBC + Dc + c4);
        bcs[row * 32 + c4 + 0] = bf16lo(v.x);
        bcs[row * 32 + c4 + 1] = bf16hi(v.x);
        bcs[row * 32 + c4 + 2] = bf16lo(v.y);
        bcs[row * 32 + c4 + 3] = bf16hi(v.y);
    }
    __syncthreads();

    float A[16];
    #pragma unroll
    for (int q = 0; q < 4; ++q)
        *(float4*)&A[q * 4] = *(const float4*)(Abuf + d * 16 + q * 4);
    const float bd = bdt[d];

    float s[16];
    #pragma unroll
    for (int n = 0; n < 16; ++n) s[n] = 0.f;

    float dc = 0.f;
    #pragma unroll 4
    for (int t = 0; t < TCH; ++t) {
        const size_t doff = (brow + t) * NDTBC + d;
        const float dt = softplusf(bf16s(dtbc + doff) + bd);
        dtbc[doff] = __float2bfloat16(dt);
        const float x = __bfloat162float(xsb[(brow + t) * Dc + d]);
        dc += dt;
        float Bt[16];
        #pragma unroll
        for (int q = 0; q < 4; ++q)
            *(float4*)&Bt[q * 4] = *(const float4*)&bcs[t * 32 + q * 4];
        #pragma unroll
        for (int n = 0; n < 16; ++n) {
            const float dA = fexp2(dt * A[n]);
            s[n] = fmaf(s[n], dA, Bt[n] * x);
        }
    }
    const size_t g = (size_t)(b * NCH + ch) * Dc + d;
    __hip_bfloat16 sb16[16];
    #pragma unroll
    for (int n = 0; n < 16; ++n) sb16[n] = __float2bfloat16(s[n]);
    *(short8v*)(S + g * 16)     = *(const short8v*)&sb16[0];
    *(short8v*)(S + g * 16 + 8) = *(const short8v*)&sb16[8];
    dcend[g] = dc;
}

// Combine: S(bf16) -> I(bf16) in place; P = exp2(dcend*A2_n). Read-before-write
// per owning thread (R10-verified discipline).
__global__ __launch_bounds__(256)
void scanB(__hip_bfloat16* __restrict__ S_io, const float* __restrict__ dcend,
           const float* __restrict__ Abuf)
{
    const int tid = blockIdx.x * 256 + threadIdx.x;
    const int n = tid & 15;
    const int d = (tid >> 4) % Dc;
    const int b = tid / (16 * Dc);
    const float An = Abuf[d * 16 + n];
    float s = 0.f;
    for (int ch = 0; ch < NCH; ++ch) {
        const size_t g = (size_t)(b * NCH + ch) * Dc + d;
        const float sv = bf16s(S_io + g * 16 + n);
        const float p  = fexp2(dcend[g] * An);
        S_io[g * 16 + n] = __float2bfloat16(s);
        s = fmaf(s, p, sv);
    }
}

__global__ __launch_bounds__(256)
void scanC(const __hip_bfloat16* __restrict__ dtbc, const __hip_bfloat16* __restrict__ xsb,
           const __hip_bfloat16* __restrict__ xz16,
           const float* __restrict__ Abuf,
           const __hip_bfloat16* __restrict__ Ibuf, const float* __restrict__ Dvec,
           __hip_bfloat16* __restrict__ ybf)
{
    const int blk = blockIdx.x;
    const int dblk = blk % 3, ch = (blk / 3) % NCH, b = blk / (3 * NCH);
    const int d = dblk * 256 + threadIdx.x;
    const int t0 = ch * TCH;
    const size_t brow = (size_t)(b * Lc + t0);

    __shared__ float bcs[TCH * 32];
    {
        const int row = threadIdx.x >> 3, c4 = (threadIdx.x & 7) * 4;
        const uint2 v = *(const uint2*)(dtbc + (brow + row) * NDTBC + Dc + c4);
        bcs[row * 32 + c4 + 0] = bf16lo(v.x);
        bcs[row * 32 + c4 + 1] = bf16hi(v.x);
        bcs[row * 32 + c4 + 2] = bf16lo(v.y);
        bcs[row * 32 + c4 + 3] = bf16hi(v.y);
    }
    __syncthreads();

    float A[16], s[16];
    #pragma unroll
    for (int q = 0; q < 4; ++q)
        *(float4*)&A[q * 4] = *(const float4*)(Abuf + d * 16 + q * 4);
    const size_t g = (size_t)(b * NCH + ch) * Dc + d;
    #pragma unroll
    for (int n = 0; n < 16; ++n) s[n] = bf16s(Ibuf + g * 16 + n);
    const float Dd = Dvec[d];

    #pragma unroll 4
    for (int t = 0; t < TCH; ++t) {
        const float dt = bf16s(dtbc + (brow + t) * NDTBC + d);   // pre-softplus'd
        const float x  = __bfloat162float(xsb[(brow + t) * Dc + d]);
        const float z  = __bfloat162float(xz16[(brow + t) * TWO_D + Dc + d]);
        float Bt[16], Ct[16];
        #pragma unroll
        for (int q = 0; q < 4; ++q) {
            *(float4*)&Bt[q * 4] = *(const float4*)&bcs[t * 32 + q * 4];
            *(float4*)&Ct[q * 4] = *(const float4*)&bcs[t * 32 + 16 + q * 4];
        }
        float yl = fmaf(Dd, x, 0.f);
        #pragma unroll
        for (int n = 0; n < 16; ++n) {
            const float dA = fexp2(dt * A[n]);
            s[n] = fmaf(s[n], dA, Bt[n] * x);
            yl = fmaf(s[n], Ct[n], yl);
        }
        ybf[(brow + t) * Dc + d] = __float2bfloat16(yl * siluf(z));
    }
}

extern "C" void kernel_launch(void* const* d_in, const int* in_sizes, int n_in,
                              void* d_out, int out_size, void* d_ws, size_t ws_size,
                              hipStream_t stream)
{
    const float* x      = (const float*)d_in[0];
    const float* state  = (const float*)d_in[1];
    const float* W_in   = (const float*)d_in[2];
    const float* conv_w = (const float*)d_in[3];
    const float* conv_b = (const float*)d_in[4];
    const float* W_x    = (const float*)d_in[5];
    const float* W_dt   = (const float*)d_in[6];
    const float* b_dt   = (const float*)d_in[7];
    const float* A_log  = (const float*)d_in[8];
    const float* Dvec   = (const float*)d_in[9];
    const float* W_out  = (const float*)d_in[10];
    float* out = (float*)d_out;

    // ---- workspace (~150 MB <= 253.75 verified) ----
    char* wsb = (char*)d_ws;
    __hip_bfloat16* xz16 = (__hip_bfloat16*)wsb;     wsb += (size_t)M_TOT * TWO_D * 2;
    __hip_bfloat16* dtbc = (__hip_bfloat16*)wsb;     wsb += (size_t)M_TOT * NDTBC * 2;
    __hip_bfloat16* Sb   = (__hip_bfloat16*)wsb;     wsb += (size_t)Bc * NCH * Dc * Nc * 2;  // bf16 S -> I
    float* dcend = (float*)wsb;                      wsb += (size_t)Bc * NCH * Dc * 4;
    __hip_bfloat16* xb  = (__hip_bfloat16*)wsb;      wsb += (size_t)M_TOT * Dc * 2;
    __hip_bfloat16* xsb = (__hip_bfloat16*)wsb;      wsb += (size_t)M_TOT * Dc * 2;
    float* Abuf = (float*)wsb;                       wsb += (size_t)Dc * Nc * 4;
    __hip_bfloat16* WinT  = (__hip_bfloat16*)wsb;    wsb += (size_t)1536 * Kd * 2;
    __hip_bfloat16* WcatT = (__hip_bfloat16*)wsb;    wsb += (size_t)NDTBC * Kd * 2;
    __hip_bfloat16* WoutT = (__hip_bfloat16*)wsb;    wsb += (size_t)768 * Kd * 2;
    __hip_bfloat16* Ib = Sb;                      // scanB in-place (verified)
    __hip_bfloat16* ybf = xb;                     // xb dead after in_proj

    // ---- prep (no memset; no templates; single fused wtrans) ----
    to_bf16_kernel<<<(M_TOT * Dc / 4 + 255) / 256, 256, 0, stream>>>(x, xb, M_TOT * Dc / 4);
    wtrans_all<<<2328, 256, 0, stream>>>(W_in, W_dt, W_x, W_out, WinT, WcatT, WoutT);
    aprep_kernel<<<(Dc * Nc + 255) / 256, 256, 0, stream>>>(A_log, Abuf);

    // 1) in_proj fused N=1536, bf16 out (BK=64)
    gemm_bf16_b16<<<dim3(TWO_D / 128, M_TOT / 128), 256, 0, stream>>>(
        xb, WinT, TWO_D, xz16);
    // 2) conv + silu -> bf16 xsb
    conv_silu_kernel<<<((M_TOT / 8) * (Dc / 2) + 255) / 256, 256, 0, stream>>>(
        xz16, conv_w, conv_b, xsb);
    // 3) fused dt|BC: dtbc = xsb @ [W_dt|W_x|pad], N=896, bf16 out
    gemm_bf16_b16<<<dim3(NDTBC / 128, M_TOT / 128), 256, 0, stream>>>(
        xsb, WcatT, NDTBC, dtbc);
    // 4) scan (bf16 dt/B/C + bf16 S/I)
    scanA<<<Bc * NCH * 3, 256, 0, stream>>>(dtbc, xsb, Abuf, b_dt, Sb, dcend);
    scanB<<<(Bc * Dc * Nc) / 256, 256, 0, stream>>>(Sb, dcend, Abuf);
    scanC<<<Bc * NCH * 3, 256, 0, stream>>>(dtbc, xsb, xz16, Abuf, Ib, Dvec, ybf);
    // 5) out = y @ W_out (N=768, fp32 out)
    gemm_bf16_f32<<<dim3(Dc / 128, M_TOT / 128), 256, 0, stream>>>(ybf, WoutT, Dc, out);
    // 6) state pass-through
    hipMemcpyAsync(out + (size_t)M_TOT * Dc, state,
                   (size_t)(Bc * Dc * Nc) * sizeof(float),
                   hipMemcpyDeviceToDevice, stream);
}